// Round 7
// baseline (147.922 us; speedup 1.0000x reference)
//
#include <hip/hip_runtime.h>
#include <hip/hip_bf16.h>
#include <math.h>

#define C    32      // attention dim
#define QD   64      // x1 channels
#define VD   64      // output channels
#define BLK  512     // sliding window block length
#define HALF 256

typedef __attribute__((ext_vector_type(8))) short bf16x8;
typedef __attribute__((ext_vector_type(4))) float f32x4;

static __device__ inline unsigned short f2bf(float x) {
    union { float f; unsigned u; } v; v.f = x;
    unsigned r = v.u + 0x7FFFu + ((v.u >> 16) & 1u);   // RNE
    return (unsigned short)(r >> 16);
}

// pack 2 floats -> one dword holding 2 bf16 (low = a, high = b)
static __device__ inline unsigned pk2(float a, float b) {
    union { __hip_bfloat162 h; unsigned u; } x;
    x.h = __float22bfloat162_rn(make_float2(a, b));
    return x.u;
}

// ---------------- kernel 1: QKV projection ----------------
// kind 0 -> qT bf16 (L,32) pre-scaled by 1/sqrt(32)
// kind 1 -> kT bf16 (L,32)
// kind 2 -> v2 bf16 tiled: [l>>6][(l>>5)&1][ch][l&31]  (2048 elems / 64-key block)
// NOTE: same-b blocks of different kinds are 256 apart in dispatch order ->
// same XCD (256%8==0) -> x1 re-reads are L2-local. Near memory floor; leave as is.
__global__ __launch_bounds__(256) void qkv_proj(
    const float* __restrict__ x1,
    const float* __restrict__ Wq, const float* __restrict__ bq,
    const float* __restrict__ Wk, const float* __restrict__ bk,
    const float* __restrict__ Wv, const float* __restrict__ bv,
    unsigned short* __restrict__ qT, unsigned short* __restrict__ kT,
    unsigned short* __restrict__ v2, int L)
{
    const int kind = blockIdx.y;
    const float* __restrict__ W = (kind == 0) ? Wq : ((kind == 1) ? Wk : Wv);
    const float* __restrict__ b = (kind == 0) ? bq : ((kind == 1) ? bk : bv);

    const int l = blockIdx.x * 256 + threadIdx.x;

    float acc[C];
    #pragma unroll
    for (int o = 0; o < C; ++o) acc[o] = 0.f;

    #pragma unroll 4
    for (int c = 0; c < QD; ++c) {
        const float x = x1[(size_t)c * L + l];       // coalesced
        #pragma unroll
        for (int o = 0; o < C; ++o)
            acc[o] = fmaf(W[o * QD + c], x, acc[o]); // W uniform -> s_load
    }

    if (kind == 2) {
        unsigned short* dst = v2 + ((size_t)(l >> 6) << 11) + (((l >> 5) & 1) << 10) + (l & 31);
        #pragma unroll
        for (int o = 0; o < C; ++o)
            dst[o << 5] = f2bf(acc[o] + b[o]);
    } else {
        const float s = (kind == 0) ? 0.17677669529663689f : 1.0f;
        unsigned short h[C];
        #pragma unroll
        for (int o = 0; o < C; ++o) h[o] = f2bf((acc[o] + b[o]) * s);
        unsigned short* base = ((kind == 0) ? qT : kT) + (size_t)l * C;
        uint4* dst = (uint4*)base;
        const uint4* src = (const uint4*)h;
        #pragma unroll
        for (int i = 0; i < 4; ++i) dst[i] = src[i];
    }
}

// ---------------- kernel 2: MFMA flash attention, 4-way split-K ----------
// wg = 256 thr = 4 waves covering the SAME 16 queries, chunks dealt
// round-robin (deferred-sum softmax is order-independent). LPT dispatch,
// XCD-affine. One causal chunk per tile; full chunks compare/clamp-free.
__global__ __launch_bounds__(256, 8) void att_kernel(
    const unsigned short* __restrict__ qT,
    const unsigned short* __restrict__ kT,
    const unsigned short* __restrict__ v2,
    const float* __restrict__ mask,
    const float* __restrict__ Wo, const float* __restrict__ bo,
    float* __restrict__ out, int L)
{
    __shared__ float mrg[3 * 64 * 9];   // 3 writer waves x 64 lanes x (8 O + psum)

    const int tid  = threadIdx.x;
    const int lane = tid & 63;
    const int h    = tid >> 6;          // wave index within tile (0..3)
    const int lo   = lane & 15;
    const int quad = lane >> 4;

    // LPT + XCD affinity: id = (31-s)*128 + w  ->  long tiles first, id%8==w%8
    const int id = blockIdx.x;
    const int w  = id & 127;
    const int s  = 31 - (id >> 7);
    const int wq0 = w * BLK + s * 16;

    const int kstart = max(0, w * BLK - HALF);
    const int n      = ((wq0 + 15 - kstart) >> 6) + 1;   // total 64-key chunks
    const int myq    = wq0 + lo;

    // Q B-frag: B[k=c][n=q]
    const bf16x8 qB = *(const bf16x8*)(qT + (size_t)myq * C + quad * 8);

    const f32x4 zero = {0.f, 0.f, 0.f, 0.f};
    f32x4 O0 = zero, O1 = zero;
    float psum = 0.f;

    const int qsl = lo + 16 * ((quad & 1) << 1);

    // ---- full chunks (no causal masking), dealt 4-way ----
    for (int j = h; j < n - 1; j += 4) {
        const int kb = kstart + (j << 6);

        f32x4 S[4];
        float4 fm4[4];
        const unsigned short* kp = kT + (size_t)(kb + lo) * C + quad * 8;
        #pragma unroll
        for (int t = 0; t < 4; ++t) {
            const bf16x8 kA = *(const bf16x8*)(kp + (size_t)(t * 16) * C);
            S[t] = __builtin_amdgcn_mfma_f32_16x16x32_bf16(kA, qB, zero, 0, 0, 0);
            fm4[t] = *(const float4*)(mask + kb + t * 16 + quad * 4);
        }

        unsigned wp[4][2];
        #pragma unroll
        for (int t = 0; t < 4; ++t) {
            const float* fmp = (const float*)&fm4[t];
            float p[4];
            #pragma unroll
            for (int r = 0; r < 4; ++r) {
                const float pd = __expf(S[t][r]) * (fmp[r] + 1e-9f);
                psum += pd;
                p[r] = pd * fmp[r];
            }
            wp[t][0] = pk2(p[0], p[1]);
            wp[t][1] = pk2(p[2], p[3]);
        }

        const unsigned short* vbase = v2 + ((size_t)(kb >> 6) << 11);
        #pragma unroll
        for (int g = 0; g < 2; ++g) {
            union { int i[4]; bf16x8 v; } pb;
            #pragma unroll
            for (int i = 0; i < 4; ++i) {
                const int src = qsl + 16 * (i >> 1);
                const int v0 = __shfl((int)wp[2 * g][i & 1], src);
                const int v1 = __shfl((int)wp[2 * g + 1][i & 1], src);
                pb.i[i] = (quad < 2) ? v0 : v1;
            }
            const bf16x8 vA0 = *(const bf16x8*)(vbase + g * 1024 + lo * 32 + quad * 8);
            const bf16x8 vA1 = *(const bf16x8*)(vbase + g * 1024 + (16 + lo) * 32 + quad * 8);
            O0 = __builtin_amdgcn_mfma_f32_16x16x32_bf16(vA0, pb.v, O0, 0, 0, 0);
            O1 = __builtin_amdgcn_mfma_f32_16x16x32_bf16(vA1, pb.v, O1, 0, 0, 0);
        }
    }

    // ---- the single causal chunk (owner: (n-1) mod 4) ----
    if (((n - 1) & 3) == h) {
        const int kb = kstart + ((n - 1) << 6);

        f32x4 S[4];
        float4 fm4[4];
        const unsigned short* kp = kT + (size_t)(kb + lo) * C + quad * 8;
        #pragma unroll
        for (int t = 0; t < 4; ++t) {
            const bf16x8 kA = *(const bf16x8*)(kp + (size_t)(t * 16) * C);
            S[t] = __builtin_amdgcn_mfma_f32_16x16x32_bf16(kA, qB, zero, 0, 0, 0);
            fm4[t] = *(const float4*)(mask + kb + t * 16 + quad * 4);
        }

        unsigned wp[4][2];
        #pragma unroll
        for (int t = 0; t < 4; ++t) {
            const float* fmp = (const float*)&fm4[t];
            float p[4];
            #pragma unroll
            for (int r = 0; r < 4; ++r) {
                const int key = kb + t * 16 + quad * 4 + r;
                const float pd = (key <= myq) ? __expf(S[t][r]) * (fmp[r] + 1e-9f) : 0.f;
                psum += pd;
                p[r] = pd * fmp[r];
            }
            wp[t][0] = pk2(p[0], p[1]);
            wp[t][1] = pk2(p[2], p[3]);
        }

        const unsigned short* vbase = v2 + ((size_t)(kb >> 6) << 11);
        #pragma unroll
        for (int g = 0; g < 2; ++g) {
            union { int i[4]; bf16x8 v; } pb;
            #pragma unroll
            for (int i = 0; i < 4; ++i) {
                const int src = qsl + 16 * (i >> 1);
                const int v0 = __shfl((int)wp[2 * g][i & 1], src);
                const int v1 = __shfl((int)wp[2 * g + 1][i & 1], src);
                pb.i[i] = (quad < 2) ? v0 : v1;
            }
            const bf16x8 vA0 = *(const bf16x8*)(vbase + g * 1024 + lo * 32 + quad * 8);
            const bf16x8 vA1 = *(const bf16x8*)(vbase + g * 1024 + (16 + lo) * 32 + quad * 8);
            O0 = __builtin_amdgcn_mfma_f32_16x16x32_bf16(vA0, pb.v, O0, 0, 0, 0);
            O1 = __builtin_amdgcn_mfma_f32_16x16x32_bf16(vA1, pb.v, O1, 0, 0, 0);
        }
    }

    // ---- merge waves 1..3 into wave0 ----
    if (h != 0) {
        float* mp = mrg + (h - 1) * (64 * 9) + lane * 9;
        #pragma unroll
        for (int r = 0; r < 4; ++r) {
            mp[r]     = O0[r];
            mp[4 + r] = O1[r];
        }
        mp[8] = psum;
    }
    __syncthreads();
    if (h != 0) return;

    #pragma unroll
    for (int u = 0; u < 3; ++u) {
        const float* mp = mrg + u * (64 * 9) + lane * 9;
        #pragma unroll
        for (int r = 0; r < 4; ++r) {
            O0[r] += mp[r];
            O1[r] += mp[4 + r];
        }
        psum += mp[8];
    }

    // ---- denominator across quads for each query col ----
    float dsum = psum;
    dsum += __shfl_xor(dsum, 16);
    dsum += __shfl_xor(dsum, 32);
    const float inv = 1.f / dsum;

    // ---- epilogue: T = relu(O^T*inv) -> B-layout via quad-permute ----
    unsigned tw[2][2];
    tw[0][0] = pk2(fmaxf(O0[0] * inv, 0.f), fmaxf(O0[1] * inv, 0.f));
    tw[0][1] = pk2(fmaxf(O0[2] * inv, 0.f), fmaxf(O0[3] * inv, 0.f));
    tw[1][0] = pk2(fmaxf(O1[0] * inv, 0.f), fmaxf(O1[1] * inv, 0.f));
    tw[1][1] = pk2(fmaxf(O1[2] * inv, 0.f), fmaxf(O1[3] * inv, 0.f));

    union { int i[4]; bf16x8 v; } tb;
    #pragma unroll
    for (int i = 0; i < 4; ++i) {
        const int src = qsl + 16 * (i >> 1);
        const int v0 = __shfl((int)tw[0][i & 1], src);
        const int v1 = __shfl((int)tw[1][i & 1], src);
        tb.i[i] = (quad < 2) ? v0 : v1;
    }

    const float mk = mask[myq];
    #pragma unroll
    for (int t = 0; t < 4; ++t) {
        float wtmp[8];
        *(float4*)&wtmp[0] = *(const float4*)(Wo + (size_t)(t * 16 + lo) * C + quad * 8);
        *(float4*)&wtmp[4] = *(const float4*)(Wo + (size_t)(t * 16 + lo) * C + quad * 8 + 4);
        union { unsigned u[4]; bf16x8 v; } wo;
        #pragma unroll
        for (int i = 0; i < 4; ++i) wo.u[i] = pk2(wtmp[2 * i], wtmp[2 * i + 1]);
        const f32x4 R = __builtin_amdgcn_mfma_f32_16x16x32_bf16(wo.v, tb.v, zero, 0, 0, 0);
        const float4 bo4 = *(const float4*)(bo + t * 16 + quad * 4);
        const float* bop = (const float*)&bo4;
        #pragma unroll
        for (int r = 0; r < 4; ++r)
            out[(size_t)(t * 16 + quad * 4 + r) * L + myq] = (R[r] + bop[r]) * mk;
    }
}

extern "C" void kernel_launch(void* const* d_in, const int* in_sizes, int n_in,
                              void* d_out, int out_size, void* d_ws, size_t ws_size,
                              hipStream_t stream)
{
    const float* x1   = (const float*)d_in[0];
    // d_in[1] = x2 : unused (encoder stage)
    const float* mask = (const float*)d_in[2];
    const float* Wq   = (const float*)d_in[3];
    const float* bq   = (const float*)d_in[4];
    const float* Wk   = (const float*)d_in[5];
    const float* bk   = (const float*)d_in[6];
    const float* Wv   = (const float*)d_in[7];
    const float* bv   = (const float*)d_in[8];
    const float* Wo   = (const float*)d_in[9];
    const float* bo   = (const float*)d_in[10];
    float* out = (float*)d_out;

    const int L = in_sizes[0] / QD;                  // 65536
    unsigned short* qT = (unsigned short*)d_ws;      // L*32 bf16
    unsigned short* kT = qT + (size_t)L * C;         // L*32 bf16
    unsigned short* v2 = kT + (size_t)L * C;         // L*32 bf16 (tiled)

    hipLaunchKernelGGL(qkv_proj, dim3(L / 256, 3), dim3(256), 0, stream,
                       x1, Wq, bq, Wk, bk, Wv, bv, qT, kT, v2, L);

    // one wg per 16-query tile: L/16 = 4096 wgs (4 waves each, 4-way split-K)
    hipLaunchKernelGGL(att_kernel, dim3(L / 16), dim3(256), 0, stream,
                       qT, kT, v2, mask, Wo, bo, out, L);
}